// Round 11
// baseline (232.325 us; speedup 1.0000x reference)
//
#include <hip/hip_runtime.h>
#include <hip/hip_bf16.h>

// N=50000 nodes, R<=16 relations, H=64 hidden, L=32 labels, E=1.6M edges
// Zero-global-atomic pipeline:
//   p1_hist -> scan_a -> scan_b -> p1_scatter : dst-bucket partition (LDS atomics)
//   p2_sort: single-pass LDS-staged counting sort + 2048-bin (d,rel) histogram
//            -> esort, start, deg, invtT
//   layer1_gather: wave/dst, float4 lanes (e4*16+h4); 32 edges (8 dwordx4) in flight
//   zgemm: 8 nodes/block-iter, weights in regs, bf162 packed stores
//   layer2_gather: 2048 blocks, ~6 dsts/wave; root2/bias2 preloaded in regs;
//                  bf162 lanes (q*16+m); 32 edges (8 loads) in flight; fused sigmoid

#define BKT_BITS 7
#define BKT_SIZE 128
#define NB1 512
#define P2CAP 6144

__global__ void p1_hist(const int* __restrict__ dst, int* __restrict__ gh,
                        int E, int C, int nbkt) {
    __shared__ int h[512];
    int t = threadIdx.x;
    for (int i = t; i < nbkt; i += 256) h[i] = 0;
    __syncthreads();
    int b = blockIdx.x;
    int lo = b * C, hi = min(E, lo + C);
    for (int i = lo + t; i < hi; i += 256) atomicAdd(&h[dst[i] >> BKT_BITS], 1);
    __syncthreads();
    for (int i = t; i < nbkt; i += 256) gh[(size_t)i * NB1 + b] = h[i];
}

// block g: Hillis-Steele scan over gh[g][0..NB1) -> gb[g][b]=exclusive, totals[g]
__global__ __launch_bounds__(NB1) void scan_a(const int* __restrict__ gh,
                                              int* __restrict__ gb,
                                              int* __restrict__ totals) {
    __shared__ int buf[NB1];
    int g = blockIdx.x;
    int t = threadIdx.x;
    int v = gh[(size_t)g * NB1 + t];
    buf[t] = v;
    __syncthreads();
    for (int off = 1; off < NB1; off <<= 1) {
        int tmp = (t >= off) ? buf[t - off] : 0;
        __syncthreads();
        buf[t] += tmp;
        __syncthreads();
    }
    gb[(size_t)g * NB1 + t] = buf[t] - v;     // exclusive prefix
    if (t == NB1 - 1) totals[g] = buf[t];
}

// single block: exclusive scan of totals[0..nbkt) -> bucketStart
__global__ __launch_bounds__(512) void scan_b(const int* __restrict__ totals,
                                              int* __restrict__ bucketStart, int nbkt) {
    __shared__ int buf[512];
    int t = threadIdx.x;
    int v = (t < nbkt) ? totals[t] : 0;
    buf[t] = v;
    __syncthreads();
    for (int off = 1; off < 512; off <<= 1) {
        int tmp = (t >= off) ? buf[t - off] : 0;
        __syncthreads();
        buf[t] += tmp;
        __syncthreads();
    }
    if (t < nbkt) bucketStart[t] = buf[t] - v;
}

__global__ void p1_scatter(const int* __restrict__ src, const int* __restrict__ dst,
                           const int* __restrict__ et, const int* __restrict__ gb,
                           const int* __restrict__ bucketStart,
                           int* __restrict__ payB, int E, int C, int nbkt) {
    __shared__ int cur[512];
    int t = threadIdx.x;
    int b = blockIdx.x;
    for (int i = t; i < nbkt; i += 256) cur[i] = bucketStart[i] + gb[(size_t)i * NB1 + b];
    __syncthreads();
    int lo = b * C, hi = min(E, lo + C);
    for (int i = lo + t; i < hi; i += 256) {
        int d = dst[i];
        int p = atomicAdd(&cur[d >> BKT_BITS], 1);   // LDS atomic only
        payB[p] = ((d & (BKT_SIZE - 1)) << 24) | (et[i] << 20) | src[i];
    }
}

// one wg per bucket: single global read of payB (staged to LDS) + 2048-bin
// (d,rel) histogram -> invtT + deg + start; then LDS counting-sort scatter.
__global__ __launch_bounds__(256) void p2_sort(
        const int* __restrict__ payB, const int* __restrict__ bucketStart,
        int* __restrict__ esort, int* __restrict__ start, int* __restrict__ deg,
        float* __restrict__ invtT, int N, int E, int nbkt) {
    int g = blockIdx.x;
    int lo = bucketStart[g];
    int hi = (g + 1 < nbkt) ? bucketStart[g + 1] : E;
    int n = hi - lo;
    __shared__ int codes[P2CAP];
    __shared__ int hist2[BKT_SIZE * 16];
    __shared__ int base[BKT_SIZE], cur[BKT_SIZE], degS[BKT_SIZE];
    int t = threadIdx.x;
    bool fits = (n <= P2CAP);
    for (int i = t; i < BKT_SIZE * 16; i += 256) hist2[i] = 0;
    __syncthreads();
    if (fits) {
        for (int i = t; i < n; i += 256) {
            int v = payB[lo + i];
            codes[i] = v;                            // stage + hist in one pass
            atomicAdd(&hist2[((v >> 24) & (BKT_SIZE - 1)) * 16 + ((v >> 20) & 15)], 1);
        }
    } else {
        for (int i = t; i < n; i += 256) {
            int v = payB[lo + i];
            atomicAdd(&hist2[((v >> 24) & (BKT_SIZE - 1)) * 16 + ((v >> 20) & 15)], 1);
        }
    }
    __syncthreads();
    if (t < BKT_SIZE) {
        int d = g * BKT_SIZE + t;
        int tot = 0;
#pragma unroll
        for (int r = 0; r < 16; ++r) {
            int c = hist2[t * 16 + r];
            tot += c;
            if (d < N) invtT[(size_t)d * 16 + r] = (c > 0) ? 1.0f / (float)c : 0.0f;
        }
        base[t] = tot;
        degS[t] = tot;
    }
    __syncthreads();
    if (t == 0) {
        int run = 0;
        for (int i = 0; i < BKT_SIZE; ++i) { int v = base[i]; base[i] = run; run += v; }
    }
    __syncthreads();
    if (t < BKT_SIZE) {
        cur[t] = base[t];
        int d = g * BKT_SIZE + t;
        if (d < N) { start[d] = lo + base[t]; deg[d] = degS[t]; }
    }
    __syncthreads();
    if (fits) {
        for (int i = t; i < n; i += 256) {
            int v = codes[i];
            int p = atomicAdd(&cur[(v >> 24) & (BKT_SIZE - 1)], 1);   // LDS atomic
            esort[lo + p] = v & 0x00FFFFFF;    // (et<<20)|src
        }
    } else {
        for (int i = t; i < n; i += 256) {
            int v = payB[lo + i];
            int p = atomicAdd(&cur[(v >> 24) & (BKT_SIZE - 1)], 1);
            esort[lo + p] = v & 0x00FFFFFF;
        }
    }
}

// Wave per dst. lane = e4*16 + h4 (e4 = edge slot, h4 = h-quad). 32 edges per
// group: 8 independent dwordx4 loads in flight. Lanes >= lim hold clamped
// (valid) codes, cancelled by multiplicative masks; their loads cache-hit the
// last edge's row. All shuffles converged.
__global__ __launch_bounds__(256) void layer1_gather(
        const int* __restrict__ esort, const int* __restrict__ start,
        const int* __restrict__ deg, const float* __restrict__ invtT,
        const float* __restrict__ w1, const float* __restrict__ root1,
        const float* __restrict__ bias1, float* __restrict__ x, int N) {
    int lane = threadIdx.x & 63;
    int e4 = lane >> 4;       // 0..3
    int h4 = lane & 15;       // h = h4*4 .. h4*4+3
    int wave = (blockIdx.x * blockDim.x + threadIdx.x) >> 6;
    int nwaves = (gridDim.x * blockDim.x) >> 6;
    for (int d = wave; d < N; d += nwaves) {
        int beg = start[d];
        int dg = deg[d];
        float invc16 = invtT[(size_t)d * 16 + h4];   // lane r holds 1/cnt[r,d]
        float4 a0 = make_float4(0.f, 0.f, 0.f, 0.f);
        float4 a1 = make_float4(0.f, 0.f, 0.f, 0.f);
        float4 a2 = make_float4(0.f, 0.f, 0.f, 0.f);
        float4 a3 = make_float4(0.f, 0.f, 0.f, 0.f);
        for (int i = 0; i < dg; i += 64) {
            int v = esort[beg + min(i + lane, dg - 1)];   // coalesced, clamped
            int lim = min(64, dg - i);                    // wave-uniform
            for (int j = 0; j < lim; j += 32) {
                int c0 = __shfl(v, j + e4, 64);
                int c1 = __shfl(v, j + 4 + e4, 64);
                int c2 = __shfl(v, j + 8 + e4, 64);
                int c3 = __shfl(v, j + 12 + e4, 64);
                int c4 = __shfl(v, j + 16 + e4, 64);
                int c5 = __shfl(v, j + 20 + e4, 64);
                int c6 = __shfl(v, j + 24 + e4, 64);
                int c7 = __shfl(v, j + 28 + e4, 64);
                const float4 w0 = *(const float4*)(w1 + ((size_t)(c0 >> 20) * N + (c0 & 0xFFFFF)) * 64 + h4 * 4);
                const float4 w1v = *(const float4*)(w1 + ((size_t)(c1 >> 20) * N + (c1 & 0xFFFFF)) * 64 + h4 * 4);
                const float4 w2v = *(const float4*)(w1 + ((size_t)(c2 >> 20) * N + (c2 & 0xFFFFF)) * 64 + h4 * 4);
                const float4 w3 = *(const float4*)(w1 + ((size_t)(c3 >> 20) * N + (c3 & 0xFFFFF)) * 64 + h4 * 4);
                const float4 w4 = *(const float4*)(w1 + ((size_t)(c4 >> 20) * N + (c4 & 0xFFFFF)) * 64 + h4 * 4);
                const float4 w5 = *(const float4*)(w1 + ((size_t)(c5 >> 20) * N + (c5 & 0xFFFFF)) * 64 + h4 * 4);
                const float4 w6 = *(const float4*)(w1 + ((size_t)(c6 >> 20) * N + (c6 & 0xFFFFF)) * 64 + h4 * 4);
                const float4 w7 = *(const float4*)(w1 + ((size_t)(c7 >> 20) * N + (c7 & 0xFFFFF)) * 64 + h4 * 4);
                float f0 = __shfl(invc16, c0 >> 20, 64) * ((j + e4 < lim) ? 1.f : 0.f);
                float f1 = __shfl(invc16, c1 >> 20, 64) * ((j + 4 + e4 < lim) ? 1.f : 0.f);
                float f2 = __shfl(invc16, c2 >> 20, 64) * ((j + 8 + e4 < lim) ? 1.f : 0.f);
                float f3 = __shfl(invc16, c3 >> 20, 64) * ((j + 12 + e4 < lim) ? 1.f : 0.f);
                float f4 = __shfl(invc16, c4 >> 20, 64) * ((j + 16 + e4 < lim) ? 1.f : 0.f);
                float f5 = __shfl(invc16, c5 >> 20, 64) * ((j + 20 + e4 < lim) ? 1.f : 0.f);
                float f6 = __shfl(invc16, c6 >> 20, 64) * ((j + 24 + e4 < lim) ? 1.f : 0.f);
                float f7 = __shfl(invc16, c7 >> 20, 64) * ((j + 28 + e4 < lim) ? 1.f : 0.f);
                a0.x += w0.x * f0; a0.y += w0.y * f0; a0.z += w0.z * f0; a0.w += w0.w * f0;
                a1.x += w1v.x * f1; a1.y += w1v.y * f1; a1.z += w1v.z * f1; a1.w += w1v.w * f1;
                a2.x += w2v.x * f2; a2.y += w2v.y * f2; a2.z += w2v.z * f2; a2.w += w2v.w * f2;
                a3.x += w3.x * f3; a3.y += w3.y * f3; a3.z += w3.z * f3; a3.w += w3.w * f3;
                a0.x += w4.x * f4; a0.y += w4.y * f4; a0.z += w4.z * f4; a0.w += w4.w * f4;
                a1.x += w5.x * f5; a1.y += w5.y * f5; a1.z += w5.z * f5; a1.w += w5.w * f5;
                a2.x += w6.x * f6; a2.y += w6.y * f6; a2.z += w6.z * f6; a2.w += w6.w * f6;
                a3.x += w7.x * f7; a3.y += w7.y * f7; a3.z += w7.z * f7; a3.w += w7.w * f7;
            }
        }
        float4 acc;
        acc.x = (a0.x + a1.x) + (a2.x + a3.x);
        acc.y = (a0.y + a1.y) + (a2.y + a3.y);
        acc.z = (a0.z + a1.z) + (a2.z + a3.z);
        acc.w = (a0.w + a1.w) + (a2.w + a3.w);
        acc.x += __shfl_xor(acc.x, 16, 64); acc.y += __shfl_xor(acc.y, 16, 64);
        acc.z += __shfl_xor(acc.z, 16, 64); acc.w += __shfl_xor(acc.w, 16, 64);
        acc.x += __shfl_xor(acc.x, 32, 64); acc.y += __shfl_xor(acc.y, 32, 64);
        acc.z += __shfl_xor(acc.z, 32, 64); acc.w += __shfl_xor(acc.w, 32, 64);
        if (e4 == 0) {
            float4 rt = *(const float4*)(root1 + (size_t)d * 64 + h4 * 4);
            float4 bs = *(const float4*)(bias1 + h4 * 4);
            float4 o;
            o.x = acc.x + rt.x + bs.x; o.x = o.x > 0.f ? o.x : 0.f;
            o.y = acc.y + rt.y + bs.y; o.y = o.y > 0.f ? o.y : 0.f;
            o.z = acc.z + rt.z + bs.z; o.z = o.z > 0.f ? o.z : 0.f;
            o.w = acc.w + rt.w + bs.w; o.w = o.w > 0.f ? o.w : 0.f;
            *(float4*)(x + (size_t)d * 64 + h4 * 4) = o;
        }
    }
}

// z[n, r*32+l] = sum_h x[n,h] * w2[r,h,l], bf16 pairs. Thread t owns cols
// 2t,2t+1; 8 nodes per iter; weights in registers; xs reads are broadcasts.
__global__ __launch_bounds__(256, 2) void zgemm_kernel(
        const float* __restrict__ x, const float* __restrict__ w2,
        __hip_bfloat16* __restrict__ z, int N) {
    __shared__ float xs[8][64];
    int t = threadIdx.x;
    int c0 = t * 2, c1 = t * 2 + 1;
    float wc0[64], wc1[64];
    {
        const float* wp0 = w2 + (size_t)(c0 >> 5) * 2048 + (c0 & 31);
        const float* wp1 = w2 + (size_t)(c1 >> 5) * 2048 + (c1 & 31);
#pragma unroll
        for (int h = 0; h < 64; ++h) { wc0[h] = wp0[h * 32]; wc1[h] = wp1[h * 32]; }
    }
    __hip_bfloat162* z2 = reinterpret_cast<__hip_bfloat162*>(z);
    for (int base = blockIdx.x * 8; base < N; base += gridDim.x * 8) {
        __syncthreads();
        int nn = min(8, N - base);
        for (int k = t; k < nn * 64; k += 256) ((float*)xs)[k] = x[(size_t)base * 64 + k];
        __syncthreads();
#pragma unroll
        for (int n = 0; n < 8; ++n) {
            if (n < nn) {
                float a0 = 0.f, a1 = 0.f;
#pragma unroll
                for (int h = 0; h < 64; ++h) {
                    float xv = xs[n][h];
                    a0 += xv * wc0[h];
                    a1 += xv * wc1[h];
                }
                __hip_bfloat162 p;
                p.x = __float2bfloat16(a0);
                p.y = __float2bfloat16(a1);
                z2[(size_t)(base + n) * 256 + t] = p;
            }
        }
    }
}

// lane = q*16 + m: q = edge slot (0..3), m = l-pair (l=2m,2m+1). 32 edges per
// group via 8 bf162 loads in flight. root2/bias2 preloaded per-wave (multi-dst
// amortized). All shuffles converged.
__global__ __launch_bounds__(256) void layer2_gather(
        const int* __restrict__ esort, const int* __restrict__ start,
        const int* __restrict__ deg, const float* __restrict__ invtT,
        const __hip_bfloat16* __restrict__ z, const float* __restrict__ x,
        const float* __restrict__ root2, const float* __restrict__ bias2,
        float* __restrict__ out, int N) {
    int lane = threadIdx.x & 63;
    int q = lane >> 4;        // 0..3
    int m = lane & 15;        // l = 2m, 2m+1
    int wave = (blockIdx.x * blockDim.x + threadIdx.x) >> 6;
    int nwaves = (gridDim.x * blockDim.x) >> 6;
    const __hip_bfloat162* z2 = reinterpret_cast<const __hip_bfloat162*>(z);
    // per-wave invariants: root2 rows h = q*16+h2, cols 2m,2m+1; bias pair
    float2 rw[16];
#pragma unroll
    for (int h2 = 0; h2 < 16; ++h2)
        rw[h2] = *(const float2*)(root2 + (q * 16 + h2) * 32 + 2 * m);
    float2 b2 = *(const float2*)(bias2 + 2 * m);
    for (int d = wave; d < N; d += nwaves) {
        int beg = start[d];
        int dg = deg[d];
        float invc = invtT[(size_t)d * 16 + m];     // lane r (<16) holds 1/cnt[r,d]
        float xr = x[(size_t)d * 64 + lane];
        float axA = 0.f, ayA = 0.f, axB = 0.f, ayB = 0.f;
        float axC = 0.f, ayC = 0.f, axD = 0.f, ayD = 0.f;
        for (int i = 0; i < dg; i += 64) {
            int v = esort[beg + min(i + lane, dg - 1)];
            int lim = min(64, dg - i);                    // wave-uniform
            for (int j = 0; j < lim; j += 32) {
                int cA = __shfl(v, j + q, 64);
                int cB = __shfl(v, j + 4 + q, 64);
                int cC = __shfl(v, j + 8 + q, 64);
                int cD = __shfl(v, j + 12 + q, 64);
                int cE = __shfl(v, j + 16 + q, 64);
                int cF = __shfl(v, j + 20 + q, 64);
                int cG = __shfl(v, j + 24 + q, 64);
                int cH = __shfl(v, j + 28 + q, 64);
                __hip_bfloat162 zA = z2[((size_t)(cA & 0xFFFFF) * 16 + (cA >> 20)) * 16 + m];
                __hip_bfloat162 zB = z2[((size_t)(cB & 0xFFFFF) * 16 + (cB >> 20)) * 16 + m];
                __hip_bfloat162 zC = z2[((size_t)(cC & 0xFFFFF) * 16 + (cC >> 20)) * 16 + m];
                __hip_bfloat162 zD = z2[((size_t)(cD & 0xFFFFF) * 16 + (cD >> 20)) * 16 + m];
                __hip_bfloat162 zE = z2[((size_t)(cE & 0xFFFFF) * 16 + (cE >> 20)) * 16 + m];
                __hip_bfloat162 zF = z2[((size_t)(cF & 0xFFFFF) * 16 + (cF >> 20)) * 16 + m];
                __hip_bfloat162 zG = z2[((size_t)(cG & 0xFFFFF) * 16 + (cG >> 20)) * 16 + m];
                __hip_bfloat162 zH = z2[((size_t)(cH & 0xFFFFF) * 16 + (cH >> 20)) * 16 + m];
                float fA = __shfl(invc, cA >> 20, 64) * ((j + q < lim) ? 1.f : 0.f);
                float fB = __shfl(invc, cB >> 20, 64) * ((j + 4 + q < lim) ? 1.f : 0.f);
                float fC = __shfl(invc, cC >> 20, 64) * ((j + 8 + q < lim) ? 1.f : 0.f);
                float fD = __shfl(invc, cD >> 20, 64) * ((j + 12 + q < lim) ? 1.f : 0.f);
                float fE = __shfl(invc, cE >> 20, 64) * ((j + 16 + q < lim) ? 1.f : 0.f);
                float fF = __shfl(invc, cF >> 20, 64) * ((j + 20 + q < lim) ? 1.f : 0.f);
                float fG = __shfl(invc, cG >> 20, 64) * ((j + 24 + q < lim) ? 1.f : 0.f);
                float fH = __shfl(invc, cH >> 20, 64) * ((j + 28 + q < lim) ? 1.f : 0.f);
                axA += __bfloat162float(zA.x) * fA; ayA += __bfloat162float(zA.y) * fA;
                axB += __bfloat162float(zB.x) * fB; ayB += __bfloat162float(zB.y) * fB;
                axC += __bfloat162float(zC.x) * fC; ayC += __bfloat162float(zC.y) * fC;
                axD += __bfloat162float(zD.x) * fD; ayD += __bfloat162float(zD.y) * fD;
                axA += __bfloat162float(zE.x) * fE; ayA += __bfloat162float(zE.y) * fE;
                axB += __bfloat162float(zF.x) * fF; ayB += __bfloat162float(zF.y) * fF;
                axC += __bfloat162float(zG.x) * fG; ayC += __bfloat162float(zG.y) * fG;
                axD += __bfloat162float(zH.x) * fH; ayD += __bfloat162float(zH.y) * fH;
            }
        }
        float tx = (axA + axB) + (axC + axD);
        float ty = (ayA + ayB) + (ayC + ayD);
        // root2 matvec from registers: this lane covers h = q*16 + h2
#pragma unroll
        for (int h2 = 0; h2 < 16; ++h2) {
            float xs = __shfl(xr, q * 16 + h2, 64);
            tx += xs * rw[h2].x;
            ty += xs * rw[h2].y;
        }
        tx += __shfl_xor(tx, 16, 64); ty += __shfl_xor(ty, 16, 64);
        tx += __shfl_xor(tx, 32, 64); ty += __shfl_xor(ty, 32, 64);
        if (q == 0) {
            float2 o;
            o.x = 1.0f / (1.0f + __expf(-(tx + b2.x)));
            o.y = 1.0f / (1.0f + __expf(-(ty + b2.y)));
            *(float2*)(out + (size_t)d * 32 + 2 * m) = o;
        }
    }
}

// ---------------- fallback path (small workspace): round-2 verified atomics ----
__global__ void count_kernel(const int* __restrict__ dst, const int* __restrict__ et,
                             int* __restrict__ cnt, int E, int N) {
    int i = blockIdx.x * blockDim.x + threadIdx.x;
    int stride = gridDim.x * blockDim.x;
    for (; i < E; i += stride) atomicAdd(&cnt[et[i] * N + dst[i]], 1);
}
__global__ void layer1_kernel(const int* __restrict__ src, const int* __restrict__ dst,
                              const int* __restrict__ et, const int* __restrict__ cnt,
                              const float* __restrict__ w1, float* __restrict__ h1,
                              int E, int N) {
    int lane = threadIdx.x & 63;
    int wave = (blockIdx.x * blockDim.x + threadIdx.x) >> 6;
    int nwaves = (gridDim.x * blockDim.x) >> 6;
    for (int e = wave; e < E; e += nwaves) {
        int r = et[e], s = src[e], d = dst[e];
        float inv = 1.0f / (float)cnt[r * N + d];
        atomicAdd(&h1[(size_t)d * 64 + lane], w1[((size_t)r * N + s) * 64 + lane] * inv);
    }
}
__global__ void x_kernel(float* __restrict__ h1, const float* __restrict__ root1,
                         const float* __restrict__ bias1, int NH) {
    int i = blockIdx.x * blockDim.x + threadIdx.x;
    int stride = gridDim.x * blockDim.x;
    for (; i < NH; i += stride) {
        float v = h1[i] + root1[i] + bias1[i & 63];
        h1[i] = v > 0.0f ? v : 0.0f;
    }
}
__global__ void layer2_kernel(const int* __restrict__ src, const int* __restrict__ dst,
                              const int* __restrict__ et, const int* __restrict__ cnt,
                              const float* __restrict__ x, const float* __restrict__ w2,
                              float* __restrict__ out, int E, int N) {
    int lane = threadIdx.x & 63;
    int l = lane & 31;
    int half = lane >> 5;
    int wave = (blockIdx.x * blockDim.x + threadIdx.x) >> 6;
    int nwaves = (gridDim.x * blockDim.x) >> 6;
    for (int e = wave; e < E; e += nwaves) {
        int r = et[e], s = src[e], d = dst[e];
        float inv = 1.0f / (float)cnt[r * N + d];
        float xv = x[(size_t)s * 64 + lane];
        const float* w2r = w2 + ((size_t)r * 64 + half * 32) * 32 + l;
        float acc = 0.0f;
#pragma unroll
        for (int i2 = 0; i2 < 32; ++i2) acc += __shfl(xv, half * 32 + i2, 64) * w2r[(size_t)i2 * 32];
        acc += __shfl_xor(acc, 32, 64);
        if (half == 0) atomicAdd(&out[(size_t)d * 32 + l], acc * inv);
    }
}
__global__ void final_kernel(float* __restrict__ out, const float* __restrict__ x,
                             const float* __restrict__ root2, const float* __restrict__ bias2,
                             int N) {
    int idx = blockIdx.x * blockDim.x + threadIdx.x;
    int stride = gridDim.x * blockDim.x;
    int total = N * 32;
    for (; idx < total; idx += stride) {
        int n = idx >> 5, l = idx & 31;
        float acc = out[idx] + bias2[l];
        const float* xr = x + (size_t)n * 64;
#pragma unroll
        for (int h = 0; h < 64; ++h) acc += xr[h] * root2[h * 32 + l];
        out[idx] = 1.0f / (1.0f + __expf(-acc));
    }
}

extern "C" void kernel_launch(void* const* d_in, const int* in_sizes, int n_in,
                              void* d_out, int out_size, void* d_ws, size_t ws_size,
                              hipStream_t stream) {
    const int*   edge_index = (const int*)d_in[0];   // [2, E]
    const int*   edge_type  = (const int*)d_in[1];   // [E]
    const float* w1         = (const float*)d_in[2]; // [R, N, 64]
    const float* root1      = (const float*)d_in[3]; // [N, 64]
    const float* bias1      = (const float*)d_in[4]; // [64]
    const float* w2         = (const float*)d_in[5]; // [R, 64, 32]
    const float* root2      = (const float*)d_in[6]; // [64, 32]
    const float* bias2      = (const float*)d_in[7]; // [32]
    float* out = (float*)d_out;

    int E = in_sizes[1];
    int H = in_sizes[4];            // 64
    int L = in_sizes[7];            // 32
    int N = in_sizes[3] / H;
    int R = in_sizes[5] / (H * L);  // <= 16

    const int* src = edge_index;
    const int* dst = edge_index + E;

    int nbkt = (N + BKT_SIZE - 1) / BKT_SIZE;   // 391 for N=50000
    int C = (E + NB1 - 1) / NB1;                // edges per phase-1 block

    // ws layout: [gh nbkt*NB1][gb nbkt*NB1][totals nbkt][bucketStart nbkt]
    //            [payB E][esort E][invtT N*16 f32][start N][deg N][x N*64][z N*16*32 bf16]
    size_t off_gh    = 0;
    size_t off_gb    = off_gh + (size_t)nbkt * NB1 * 4;
    size_t off_tot   = off_gb + (size_t)nbkt * NB1 * 4;
    size_t off_bs    = off_tot + (size_t)nbkt * 4;
    size_t off_payB  = off_bs + (size_t)nbkt * 4 + 64;
    size_t off_esort = off_payB + (size_t)E * 4;
    size_t off_invt  = off_esort + (size_t)E * 4;
    size_t off_start = off_invt + (size_t)N * 16 * 4;
    size_t off_deg   = off_start + (size_t)N * 4;
    size_t off_x     = off_deg + (size_t)N * 4;
    size_t off_z     = off_x + (size_t)N * H * 4;
    size_t need      = off_z + (size_t)N * 16 * L * 2;

    char* ws = (char*)d_ws;
    if (ws_size >= need && R <= 16 && nbkt <= 512 && N < (1 << 20)) {
        int*   gh    = (int*)(ws + off_gh);
        int*   gb    = (int*)(ws + off_gb);
        int*   tot   = (int*)(ws + off_tot);
        int*   bs    = (int*)(ws + off_bs);
        int*   payB  = (int*)(ws + off_payB);
        int*   esort = (int*)(ws + off_esort);
        float* invtT = (float*)(ws + off_invt);
        int*   start = (int*)(ws + off_start);
        int*   deg   = (int*)(ws + off_deg);
        float* x     = (float*)(ws + off_x);
        __hip_bfloat16* z = (__hip_bfloat16*)(ws + off_z);

        p1_hist      <<<NB1, 256, 0, stream>>>(dst, gh, E, C, nbkt);
        scan_a       <<<nbkt, NB1, 0, stream>>>(gh, gb, tot);
        scan_b       <<<1, 512, 0, stream>>>(tot, bs, nbkt);
        p1_scatter   <<<NB1, 256, 0, stream>>>(src, dst, edge_type, gb, bs, payB, E, C, nbkt);
        p2_sort      <<<nbkt, 256, 0, stream>>>(payB, bs, esort, start, deg, invtT, N, E, nbkt);
        layer1_gather<<<(N + 3) / 4, 256, 0, stream>>>(esort, start, deg, invtT, w1, root1, bias1, x, N);
        zgemm_kernel <<<2048, 256, 0, stream>>>(x, w2, z, N);
        layer2_gather<<<2048, 256, 0, stream>>>(esort, start, deg, invtT, z, x, root2, bias2, out, N);
    } else {
        // fallback: round-2 verified atomic path (needs ~16 MB)
        size_t cnt_bytes = (size_t)R * N * sizeof(int);
        int*   cnt = (int*)ws;
        float* h1  = (float*)(ws + cnt_bytes);
        hipMemsetAsync(cnt, 0, cnt_bytes + (size_t)N * H * sizeof(float), stream);
        hipMemsetAsync(out, 0, (size_t)N * L * sizeof(float), stream);
        count_kernel <<<2048, 256, 0, stream>>>(dst, edge_type, cnt, E, N);
        layer1_kernel<<<4096, 256, 0, stream>>>(src, dst, edge_type, cnt, w1, h1, E, N);
        x_kernel     <<<2048, 256, 0, stream>>>(h1, root1, bias1, N * H);
        layer2_kernel<<<4096, 256, 0, stream>>>(src, dst, edge_type, cnt, h1, w2, out, E, N);
        final_kernel <<<2048, 256, 0, stream>>>(out, h1, root2, bias2, N);
    }
}